// Round 4
// baseline (1127.738 us; speedup 1.0000x reference)
//
#include <hip/hip_runtime.h>
#include <stdint.h>

// MixtureOfSoftmaxes: B=1024, H=4, D=256, V=100000
// out[b,v] = sum_h pi[b,h] * softmax_v(proj[b,h,:]·emb[v,:])
// No-max softmax (|logits| < ~3):
//   pass C: part[strip2][m] = sum_{v in strip,vh} exp(l[m,v]); reduce -> w = pi/s
//   pass D: out[b,v] = sum_h w[m]*exp(l[m,v])
// R4: barrier-free GEMM. A (projA, 2MB, L2-resident) loaded per-wave directly
// into a register double-buffer (no LDS, no barriers). emb fragments register-
// resident for full K=256. Persistent 256-block grid, leftover strips split
// per-m-tile for load balance.

#define VOCAB 100000
#define NSTRIPS 1564  // 782 v-strips x 2 vh halves

typedef __attribute__((ext_vector_type(8))) short short8;
typedef __attribute__((ext_vector_type(4))) float f32x4;

__device__ __forceinline__ short f2bf(float f) {
  uint32_t u = __float_as_uint(f);
  u = (u + 0x7FFFu + ((u >> 16) & 1u)) >> 16;
  return (short)u;
}

// ---------------- kernel 1: proj = tanh(x @ proj_mat^T) -> bf16 [4096 x 256] ----
__global__ __launch_bounds__(256) void proj_kernel(const float* __restrict__ x,
                                                   const float* __restrict__ pm,
                                                   short* __restrict__ projA) {
  __shared__ float xs[64][36];
  __shared__ float ps[64][36];
  const int tid = threadIdx.x;
  const int tx = tid & 15, ty = tid >> 4;
  const int m0 = blockIdx.y * 64, n0 = blockIdx.x * 64;
  float acc[4][4];
#pragma unroll
  for (int i = 0; i < 4; i++)
#pragma unroll
    for (int j = 0; j < 4; j++) acc[i][j] = 0.f;

  for (int k0 = 0; k0 < 256; k0 += 32) {
    const int r = tid >> 2, c = (tid & 3) * 8;
    *(float4*)&xs[r][c]     = *(const float4*)&x[(m0 + r) * 256 + k0 + c];
    *(float4*)&xs[r][c + 4] = *(const float4*)&x[(m0 + r) * 256 + k0 + c + 4];
    *(float4*)&ps[r][c]     = *(const float4*)&pm[(n0 + r) * 256 + k0 + c];
    *(float4*)&ps[r][c + 4] = *(const float4*)&pm[(n0 + r) * 256 + k0 + c + 4];
    __syncthreads();
#pragma unroll
    for (int kk = 0; kk < 32; kk += 4) {
      float4 xa[4], pb[4];
#pragma unroll
      for (int i = 0; i < 4; i++) xa[i] = *(const float4*)&xs[ty * 4 + i][kk];
#pragma unroll
      for (int j = 0; j < 4; j++) pb[j] = *(const float4*)&ps[tx * 4 + j][kk];
#pragma unroll
      for (int i = 0; i < 4; i++)
#pragma unroll
        for (int j = 0; j < 4; j++)
          acc[i][j] += xa[i].x * pb[j].x + xa[i].y * pb[j].y +
                       xa[i].z * pb[j].z + xa[i].w * pb[j].w;
    }
    __syncthreads();
  }
#pragma unroll
  for (int i = 0; i < 4; i++)
#pragma unroll
    for (int j = 0; j < 4; j++)
      projA[(size_t)(m0 + ty * 4 + i) * 1024 + (n0 + tx * 4 + j)] = f2bf(tanhf(acc[i][j]));
}

// ---------------- kernel 2: pi = softmax(x @ mix_mat^T)  [1024 x 4] --------------
__global__ __launch_bounds__(256) void pi_kernel(const float* __restrict__ x,
                                                 const float* __restrict__ mm,
                                                 float* __restrict__ pi) {
  int b = blockIdx.x * 256 + threadIdx.x;
  if (b >= 1024) return;
  float acc[4] = {0.f, 0.f, 0.f, 0.f};
  for (int k = 0; k < 256; k += 4) {
    float4 xv = *(const float4*)&x[(size_t)b * 256 + k];
#pragma unroll
    for (int h = 0; h < 4; h++) {
      float4 mv = *(const float4*)&mm[h * 256 + k];
      acc[h] += xv.x * mv.x + xv.y * mv.y + xv.z * mv.z + xv.w * mv.w;
    }
  }
  float mx = fmaxf(fmaxf(acc[0], acc[1]), fmaxf(acc[2], acc[3]));
  float e[4], ssum = 0.f;
#pragma unroll
  for (int h = 0; h < 4; h++) { e[h] = __expf(acc[h] - mx); ssum += e[h]; }
#pragma unroll
  for (int h = 0; h < 4; h++) pi[b * 4 + h] = e[h] / ssum;
}

// ---------------- big GEMM helpers ----------------------------------------------
__device__ __forceinline__ void load_Bf(short8 (&Bf)[4][8], const float* __restrict__ emb,
                                        int s, int vh, int l15, int l4) {
#pragma unroll
  for (int ni = 0; ni < 4; ++ni) {
    int v = s * 128 + vh * 64 + ni * 16 + l15;
    v = (v < VOCAB) ? v : (VOCAB - 1);
    const float* src = emb + (size_t)v * 256 + l4 * 8;
#pragma unroll
    for (int ks = 0; ks < 8; ++ks) {
      float4 f0 = *(const float4*)(src + ks * 32);
      float4 f1 = *(const float4*)(src + ks * 32 + 4);
      short8 b8;
      b8[0] = f2bf(f0.x); b8[1] = f2bf(f0.y); b8[2] = f2bf(f0.z); b8[3] = f2bf(f0.w);
      b8[4] = f2bf(f1.x); b8[5] = f2bf(f1.y); b8[6] = f2bf(f1.z); b8[7] = f2bf(f1.w);
      Bf[ni][ks] = b8;
    }
  }
}

// A-fragment half-tile (2 mi x 4 k-chunks) direct from global (L2) into regs.
__device__ __forceinline__ void load_half(short8 (&A)[2][4], const short* aptr, int t, int h) {
#pragma unroll
  for (int mi = 0; mi < 2; ++mi)
#pragma unroll
    for (int k = 0; k < 4; ++k)
      A[mi][k] = *(const short8*)(aptr + (size_t)t * 32768 + mi * 4096 + (h * 4 + k) * 32);
}

__device__ __forceinline__ void mfma_half(const short8 (&A)[2][4], const short8 (&Bf)[4][8],
                                          int h, f32x4 (&acc)[2][4]) {
  __builtin_amdgcn_s_setprio(1);
#pragma unroll
  for (int k = 0; k < 4; ++k)
#pragma unroll
    for (int mi = 0; mi < 2; ++mi)
#pragma unroll
      for (int ni = 0; ni < 4; ++ni)
        acc[mi][ni] = __builtin_amdgcn_mfma_f32_16x16x32_bf16(A[mi][k], Bf[ni][h * 4 + k],
                                                              acc[mi][ni], 0, 0, 0);
  __builtin_amdgcn_s_setprio(0);
}

// one v-strip (128 v: vh halves of 64), m-tiles t0..t1-1 (128 m-rows each)
template <int MODE>
__device__ __forceinline__ void run_strip(int s, int t0, int t1, const short8 (&Bf)[4][8],
                                          const short* aptr, int mq, int vh, int l15, int l4,
                                          int lane, const float* __restrict__ w,
                                          float* __restrict__ part, float* __restrict__ dump,
                                          float* __restrict__ out) {
  f32x4 acc[2][4];
#pragma unroll
  for (int mi = 0; mi < 2; ++mi)
#pragma unroll
    for (int ni = 0; ni < 4; ++ni) acc[mi][ni] = (f32x4){0.f, 0.f, 0.f, 0.f};

  short8 A0[2][4], A1[2][4];
  load_half(A0, aptr, t0, 0);
  load_half(A1, aptr, t0, 1);

#pragma unroll 1
  for (int t = t0; t < t1; ++t) {
    mfma_half(A0, Bf, 0, acc);
    load_half(A0, aptr, t + 1, 0);  // overrun read at strip end lands in ws: harmless
    mfma_half(A1, Bf, 1, acc);
    load_half(A1, aptr, t + 1, 1);

    if (MODE == 0) {
#pragma unroll
      for (int mi = 0; mi < 2; ++mi) {
        float p[4];
#pragma unroll
        for (int r = 0; r < 4; ++r) {
          float q = 0.f;
#pragma unroll
          for (int ni = 0; ni < 4; ++ni) {
            int v = s * 128 + vh * 64 + ni * 16 + l15;
            float e = __expf(acc[mi][ni][r]);
            q += (v < VOCAB) ? e : 0.f;
          }
          q += __shfl_xor(q, 1, 64);
          q += __shfl_xor(q, 2, 64);
          q += __shfl_xor(q, 4, 64);
          q += __shfl_xor(q, 8, 64);
          p[r] = q;
        }
        if (l15 == 0) {
          int m = t * 128 + mq * 32 + mi * 16 + l4 * 4;
#pragma unroll
          for (int r = 0; r < 4; ++r)
            part[(size_t)(s * 2 + vh) * 4096 + m + r] = p[r];
        }
      }
    } else {
#pragma unroll
      for (int mi = 0; mi < 2; ++mi) {
        int m = t * 128 + mq * 32 + mi * 16 + l4 * 4;  // multiple of 4
        float4 wv = *(const float4*)&w[m];
#pragma unroll
        for (int ni = 0; ni < 4; ++ni) {
          int v = s * 128 + vh * 64 + ni * 16 + l15;
          float val = wv.x * __expf(acc[mi][ni][0]) + wv.y * __expf(acc[mi][ni][1]) +
                      wv.z * __expf(acc[mi][ni][2]) + wv.w * __expf(acc[mi][ni][3]);
          float* tgt = (v < VOCAB) ? (out + (size_t)(m >> 2) * VOCAB + v) : (dump + lane);
          *tgt = val;  // fire-and-forget
        }
      }
    }
#pragma unroll
    for (int mi = 0; mi < 2; ++mi)
#pragma unroll
      for (int ni = 0; ni < 4; ++ni) acc[mi][ni] = (f32x4){0.f, 0.f, 0.f, 0.f};
  }
}

// persistent grid: 256 blocks (1/CU), 8 waves each: mq=wid&3 (m-quarter), vh=wid>>2.
// strips 0..767: 3 per block. strips 768..781: split into 448 single-tile units.
template <int MODE>
__global__ __launch_bounds__(512, 2) void mos_gemm(const float* __restrict__ emb,
                                                   const short* __restrict__ projA,
                                                   const float* __restrict__ w,
                                                   float* __restrict__ part,
                                                   float* __restrict__ dump,
                                                   float* __restrict__ out) {
  const int tid = threadIdx.x;
  const int lane = tid & 63, wid = tid >> 6;
  const int mq = wid & 3, vh = wid >> 2;
  const int l15 = lane & 15, l4 = lane >> 4;
  const int bid = blockIdx.x;
  const short* aptr = projA + (mq * 32 + l15) * 256 + l4 * 8;

  short8 Bf[4][8];  // emb fragments, full K=256, register-resident
#pragma unroll 1
  for (int s = bid; s < 768; s += 256) {
    load_Bf(Bf, emb, s, vh, l15, l4);
    run_strip<MODE>(s, 0, 32, Bf, aptr, mq, vh, l15, l4, lane, w, part, dump, out);
  }
#pragma unroll 1
  for (int u = bid; u < 448; u += 256) {
    int s = 768 + (u >> 5), t = u & 31;
    load_Bf(Bf, emb, s, vh, l15, l4);
    run_strip<MODE>(s, t, t + 1, Bf, aptr, mq, vh, l15, l4, lane, w, part, dump, out);
  }
}

// ---------------- reduce partials + w = pi / s ----------------------------------
__global__ __launch_bounds__(256) void reduce_w(const float* __restrict__ part,
                                                const float* __restrict__ pi,
                                                float* __restrict__ w) {
  int m = blockIdx.x * 256 + threadIdx.x;  // 0..4095
  float sum = 0.f;
#pragma unroll 16
  for (int c = 0; c < NSTRIPS; ++c) sum += part[(size_t)c * 4096 + m];
  w[m] = pi[m] / sum;
}

extern "C" void kernel_launch(void* const* d_in, const int* in_sizes, int n_in,
                              void* d_out, int out_size, void* d_ws, size_t ws_size,
                              hipStream_t stream) {
  const float* x        = (const float*)d_in[0];
  const float* proj_mat = (const float*)d_in[1];
  const float* mix_mat  = (const float*)d_in[2];
  const float* emb      = (const float*)d_in[3];
  float* out = (float*)d_out;

  char* ws = (char*)d_ws;
  short* projA = (short*)ws;                         // bf16 [4096][256] = 2 MB
  float* pi    = (float*)(ws + (2u << 20));          // [4096]
  float* w     = (float*)(ws + (2u << 20) + 16384);  // [4096]
  float* part  = (float*)(ws + (2u << 20) + 32768);  // [1564][4096] = 25.6 MB
  float* dump  = part + (size_t)NSTRIPS * 4096;      // 16 KB junk sink

  dim3 g1(16, 16);
  proj_kernel<<<g1, 256, 0, stream>>>(x, proj_mat, projA);
  pi_kernel<<<4, 256, 0, stream>>>(x, mix_mat, pi);

  mos_gemm<0><<<256, 512, 0, stream>>>(emb, projA, nullptr, part, dump, nullptr);
  reduce_w<<<16, 256, 0, stream>>>(part, pi, w);
  mos_gemm<1><<<256, 512, 0, stream>>>(emb, projA, w, nullptr, dump, out);
}

// Round 5
// 684.233 us; speedup vs baseline: 1.6482x; 1.6482x over previous
//
#include <hip/hip_runtime.h>
#include <stdint.h>

// MixtureOfSoftmaxes: B=1024, H=4, D=256, V=100000
// out[b,v] = sum_h pi[b,h] * softmax_v(proj[b,h,:]·emb[v,:])
// No-max softmax (|logits| < ~3):
//   pass C: part[vb][m] = sum_{v in vb} exp(l[m,v]); reduce -> w = pi/s
//   pass D: out[b,v] = sum_h w[m]*exp(l[m,v])
// R5: m201-style 256x256 8-phase GEMM, BK=64, 512 thr (2x4 waves), LDS 128KB
// double-buffered, global_load_lds w/ pre-swizzled source, counted waits,
// emb pre-converted to bf16 (embB) so both operands stage via global_load_lds.

#define VOCAB 100000
#define NVB 391      // v-blocks of 256 (covers 100096)
#define VPAD 100096

typedef __attribute__((ext_vector_type(8))) short short8;
typedef __attribute__((ext_vector_type(4))) float f32x4;

__device__ __forceinline__ short f2bf(float f) {
  uint32_t u = __float_as_uint(f);
  u = (u + 0x7FFFu + ((u >> 16) & 1u)) >> 16;
  return (short)u;
}

#define VMCNT0() asm volatile("s_waitcnt vmcnt(0)" ::: "memory")
#define LGKM0()  asm volatile("s_waitcnt lgkmcnt(0)" ::: "memory")
#define SCHED0() __builtin_amdgcn_sched_barrier(0)
#define BAR()    __builtin_amdgcn_s_barrier()

// ---------------- kernel 1: proj = tanh(x @ proj_mat^T) -> bf16 [4096 x 256] ----
__global__ __launch_bounds__(256) void proj_kernel(const float* __restrict__ x,
                                                   const float* __restrict__ pm,
                                                   short* __restrict__ projA) {
  __shared__ float xs[64][36];
  __shared__ float ps[64][36];
  const int tid = threadIdx.x;
  const int tx = tid & 15, ty = tid >> 4;
  const int m0 = blockIdx.y * 64, n0 = blockIdx.x * 64;
  float acc[4][4];
#pragma unroll
  for (int i = 0; i < 4; i++)
#pragma unroll
    for (int j = 0; j < 4; j++) acc[i][j] = 0.f;

  for (int k0 = 0; k0 < 256; k0 += 32) {
    const int r = tid >> 2, c = (tid & 3) * 8;
    *(float4*)&xs[r][c]     = *(const float4*)&x[(m0 + r) * 256 + k0 + c];
    *(float4*)&xs[r][c + 4] = *(const float4*)&x[(m0 + r) * 256 + k0 + c + 4];
    *(float4*)&ps[r][c]     = *(const float4*)&pm[(n0 + r) * 256 + k0 + c];
    *(float4*)&ps[r][c + 4] = *(const float4*)&pm[(n0 + r) * 256 + k0 + c + 4];
    __syncthreads();
#pragma unroll
    for (int kk = 0; kk < 32; kk += 4) {
      float4 xa[4], pb[4];
#pragma unroll
      for (int i = 0; i < 4; i++) xa[i] = *(const float4*)&xs[ty * 4 + i][kk];
#pragma unroll
      for (int j = 0; j < 4; j++) pb[j] = *(const float4*)&ps[tx * 4 + j][kk];
#pragma unroll
      for (int i = 0; i < 4; i++)
#pragma unroll
        for (int j = 0; j < 4; j++)
          acc[i][j] += xa[i].x * pb[j].x + xa[i].y * pb[j].y +
                       xa[i].z * pb[j].z + xa[i].w * pb[j].w;
    }
    __syncthreads();
  }
#pragma unroll
  for (int i = 0; i < 4; i++)
#pragma unroll
    for (int j = 0; j < 4; j++)
      projA[(size_t)(m0 + ty * 4 + i) * 1024 + (n0 + tx * 4 + j)] = f2bf(tanhf(acc[i][j]));
}

// ---------------- kernel 2: pi = softmax(x @ mix_mat^T)  [1024 x 4] --------------
__global__ __launch_bounds__(256) void pi_kernel(const float* __restrict__ x,
                                                 const float* __restrict__ mm,
                                                 float* __restrict__ pi) {
  int b = blockIdx.x * 256 + threadIdx.x;
  if (b >= 1024) return;
  float acc[4] = {0.f, 0.f, 0.f, 0.f};
  for (int k = 0; k < 256; k += 4) {
    float4 xv = *(const float4*)&x[(size_t)b * 256 + k];
#pragma unroll
    for (int h = 0; h < 4; h++) {
      float4 mv = *(const float4*)&mm[h * 256 + k];
      acc[h] += xv.x * mv.x + xv.y * mv.y + xv.z * mv.z + xv.w * mv.w;
    }
  }
  float mx = fmaxf(fmaxf(acc[0], acc[1]), fmaxf(acc[2], acc[3]));
  float e[4], ssum = 0.f;
#pragma unroll
  for (int h = 0; h < 4; h++) { e[h] = __expf(acc[h] - mx); ssum += e[h]; }
#pragma unroll
  for (int h = 0; h < 4; h++) pi[b * 4 + h] = e[h] / ssum;
}

// ---------------- kernel 3: embB = bf16(emb), zero-padded to VPAD rows -----------
__global__ __launch_bounds__(256) void embB_kernel(const float* __restrict__ emb,
                                                   short* __restrict__ embB) {
  size_t i = ((size_t)blockIdx.x * 256 + threadIdx.x) * 8;  // element index
  size_t row = i >> 8;
  short8 b8;
  if (row < VOCAB) {
    float4 f0 = *(const float4*)&emb[i];
    float4 f1 = *(const float4*)&emb[i + 4];
    b8[0] = f2bf(f0.x); b8[1] = f2bf(f0.y); b8[2] = f2bf(f0.z); b8[3] = f2bf(f0.w);
    b8[4] = f2bf(f1.x); b8[5] = f2bf(f1.y); b8[6] = f2bf(f1.z); b8[7] = f2bf(f1.w);
  } else {
#pragma unroll
    for (int j = 0; j < 8; ++j) b8[j] = 0;
  }
  *(short8*)&embB[i] = b8;
}

// ---------------- big GEMM: 256x256 tile, BK=64, 8-phase-style schedule ---------
// LDS buffer b (0/1) at b*65536: A-tile 256x64 bf16 (32KB) at +0, B-tile at +32768.
// Row = 128 B = 8 chunks of 16 B; chunk swizzle: c' = c ^ (row & 7).

template <int KT>  // stages K-step KT+1 into buffer (KT+1)&1
__device__ __forceinline__ void stage_A(const char* gA, char* sm, int wid) {
  constexpr int NXT = (KT + 1) & 1;
#pragma unroll
  for (int h = 0; h < 2; ++h)
#pragma unroll
    for (int j = 0; j < 2; ++j)
      __builtin_amdgcn_global_load_lds(
          (const __attribute__((address_space(1))) void*)(gA + (KT + 1) * 128 + h * 65536 + j * 32768),
          (__attribute__((address_space(3))) void*)(sm + NXT * 65536 + h * 16384 + j * 8192 + wid * 1024),
          16, 0, 0);
}
template <int KT>
__device__ __forceinline__ void stage_B(const char* gB, char* sm, int wid) {
  constexpr int NXT = (KT + 1) & 1;
#pragma unroll
  for (int h = 0; h < 2; ++h)
#pragma unroll
    for (int j = 0; j < 2; ++j)
      __builtin_amdgcn_global_load_lds(
          (const __attribute__((address_space(1))) void*)(gB + (KT + 1) * 128 + h * 65536 + j * 32768),
          (__attribute__((address_space(3))) void*)(sm + NXT * 65536 + 32768 + h * 16384 + j * 8192 + wid * 1024),
          16, 0, 0);
}

#define MFMA_CLUSTER(AHALF, BSEL, MOFF, NOFF)                                              \
  __builtin_amdgcn_s_setprio(1);                                                           \
  _Pragma("unroll") for (int ks = 0; ks < 2; ++ks)                                         \
      _Pragma("unroll") for (int i = 0; i < 4; ++i)                                        \
          _Pragma("unroll") for (int j = 0; j < 2; ++j)                                    \
              acc[(MOFF) + i][(NOFF) + j] = __builtin_amdgcn_mfma_f32_16x16x32_bf16(       \
                  AHALF[i][ks], BSEL[j][ks], acc[(MOFF) + i][(NOFF) + j], 0, 0, 0);        \
  __builtin_amdgcn_s_setprio(0);

template <int KT>
__device__ __forceinline__ void k_step(char* sm, const char* gA, const char* gB, int wid,
                                       f32x4 (&acc)[8][4], int aK0, int aK1, int bK0, int bK1) {
  constexpr int CB = (KT & 1) * 65536;
  short8 a[4][2], b0[2][2], b1[2][2];
  // ---- phase 0: read A(mh0) 8 + B(nh0) 4; stage A(kt+1); MFMA (mh0 x nh0) ----
#pragma unroll
  for (int i = 0; i < 4; ++i) {
    a[i][0] = *(const short8*)(sm + CB + aK0 + i * 2048);
    a[i][1] = *(const short8*)(sm + CB + aK1 + i * 2048);
  }
#pragma unroll
  for (int j = 0; j < 2; ++j) {
    b0[j][0] = *(const short8*)(sm + CB + bK0 + j * 2048);
    b0[j][1] = *(const short8*)(sm + CB + bK1 + j * 2048);
  }
  if (KT < 3) stage_A<KT>(gA, sm, wid);
  BAR();
  LGKM0();
  SCHED0();
  MFMA_CLUSTER(a, b0, 0, 0);
  BAR();
  // ---- phase 1: read B(nh1) 4; stage B(kt+1); MFMA (mh0 x nh1) ----
#pragma unroll
  for (int j = 0; j < 2; ++j) {
    b1[j][0] = *(const short8*)(sm + CB + bK0 + (2 + j) * 2048);
    b1[j][1] = *(const short8*)(sm + CB + bK1 + (2 + j) * 2048);
  }
  if (KT < 3) stage_B<KT>(gB, sm, wid);
  BAR();
  LGKM0();
  SCHED0();
  MFMA_CLUSTER(a, b1, 0, 2);
  BAR();
  // ---- phase 2: read A(mh1) 8; MFMA (mh1 x nh1); vmcnt-drain; barrier ----
#pragma unroll
  for (int i = 0; i < 4; ++i) {
    a[i][0] = *(const short8*)(sm + CB + aK0 + (4 + i) * 2048);
    a[i][1] = *(const short8*)(sm + CB + aK1 + (4 + i) * 2048);
  }
  BAR();
  LGKM0();
  SCHED0();
  MFMA_CLUSTER(a, b1, 4, 2);
  VMCNT0();  // stage loads are >=1.5 phases old here: near-free counted drain
  BAR();     // releases next k_step's ds_reads of buffer (KT+1)&1
  // ---- phase 3: MFMA (mh1 x nh0), pure register phase ----
  MFMA_CLUSTER(a, b0, 4, 0);
}

template <int MODE>
__global__ __launch_bounds__(512, 2) void mos_gemm8(const short* __restrict__ projA_s,
                                                    const short* __restrict__ embB_s,
                                                    const float* __restrict__ w,
                                                    float* __restrict__ part,
                                                    float* __restrict__ out) {
  __shared__ __align__(16) char sm[131072];
  const int tid = threadIdx.x;
  const int lane = tid & 63, wid = tid >> 6;
  const int wr = wid >> 2, wc = wid & 3;  // 2 (m) x 4 (v) wave grid
  const int l15 = lane & 15, l4 = lane >> 4;
  const int m0 = blockIdx.x * 256;
  const int v0 = blockIdx.y * 256;

  // per-thread staging sources (pre-swizzled so linear LDS dest = swizzled layout)
  const int cxor = ((tid & 7) ^ ((tid >> 3) & 7)) * 16;
  const char* gA = (const char*)projA_s + (size_t)(m0 + (tid >> 3)) * 512 + cxor;
  const char* gB = (const char*)embB_s + (size_t)(v0 + (tid >> 3)) * 512 + cxor;

  // per-lane ds-read offsets (within buffer 0)
  const int sA = l15 & 7;
  const int aK0 = (wr * 128 + l15) * 128 + ((l4 ^ sA) << 4);
  const int aK1 = (wr * 128 + l15) * 128 + (((4 + l4) ^ sA) << 4);
  const int bK0 = 32768 + (wc * 64 + l15) * 128 + ((l4 ^ sA) << 4);
  const int bK1 = 32768 + (wc * 64 + l15) * 128 + (((4 + l4) ^ sA) << 4);

  f32x4 acc[8][4];
#pragma unroll
  for (int i = 0; i < 8; ++i)
#pragma unroll
    for (int j = 0; j < 4; ++j) acc[i][j] = (f32x4){0.f, 0.f, 0.f, 0.f};

  // prologue: stage K-step 0 into buffer 0
  stage_A<-1>(gA, sm, wid);
  stage_B<-1>(gB, sm, wid);
  SCHED0();
  VMCNT0();
  BAR();

  k_step<0>(sm, gA, gB, wid, acc, aK0, aK1, bK0, bK1);
  k_step<1>(sm, gA, gB, wid, acc, aK0, aK1, bK0, bK1);
  k_step<2>(sm, gA, gB, wid, acc, aK0, aK1, bK0, bK1);
  k_step<3>(sm, gA, gB, wid, acc, aK0, aK1, bK0, bK1);

  if (MODE == 0) {
    // partial softmax denominators over this block's 256 v-cols
#pragma unroll
    for (int mi = 0; mi < 8; ++mi) {
      float p[4] = {0.f, 0.f, 0.f, 0.f};
#pragma unroll
      for (int ni = 0; ni < 4; ++ni) {
        int v = v0 + wc * 64 + ni * 16 + l15;
        bool ok = v < VOCAB;
#pragma unroll
        for (int r = 0; r < 4; ++r) {
          float e = __expf(acc[mi][ni][r]);
          p[r] += ok ? e : 0.f;
        }
      }
#pragma unroll
      for (int r = 0; r < 4; ++r) {
        p[r] += __shfl_xor(p[r], 1, 64);
        p[r] += __shfl_xor(p[r], 2, 64);
        p[r] += __shfl_xor(p[r], 4, 64);
        p[r] += __shfl_xor(p[r], 8, 64);
      }
      if (l15 == 0) {
        float4 pv = {p[0], p[1], p[2], p[3]};
        *(float4*)(sm + (wc * 256 + wr * 128 + mi * 16 + l4 * 4) * 4) = pv;
      }
    }
    __syncthreads();
    if (tid < 256) {
      const float* rf = (const float*)sm;
      float ssum = rf[tid] + rf[256 + tid] + rf[512 + tid] + rf[768 + tid];
      part[(size_t)blockIdx.y * 4096 + m0 + tid] = ssum;
    }
  } else {
    // out[b, v] = sum_h w[m]*exp(l);  acc regs r=0..3 are the 4 heads of one b
#pragma unroll
    for (int mi = 0; mi < 8; ++mi) {
      int mbase = m0 + wr * 128 + mi * 16;
      float4 wv = *(const float4*)&w[mbase + l4 * 4];
      size_t brow = (size_t)(mbase >> 2) + l4;
#pragma unroll
      for (int ni = 0; ni < 4; ++ni) {
        int v = v0 + wc * 64 + ni * 16 + l15;
        float val = wv.x * __expf(acc[mi][ni][0]) + wv.y * __expf(acc[mi][ni][1]) +
                    wv.z * __expf(acc[mi][ni][2]) + wv.w * __expf(acc[mi][ni][3]);
        if (v < VOCAB) out[brow * VOCAB + v] = val;
      }
    }
  }
}

// ---------------- reduce partials + w = pi / s ----------------------------------
__global__ __launch_bounds__(256) void reduce_w(const float* __restrict__ part,
                                                const float* __restrict__ pi,
                                                float* __restrict__ w) {
  int m = blockIdx.x * 256 + threadIdx.x;  // 0..4095
  float sum = 0.f;
  for (int c = 0; c < NVB; ++c) sum += part[(size_t)c * 4096 + m];
  w[m] = pi[m] / sum;
}

extern "C" void kernel_launch(void* const* d_in, const int* in_sizes, int n_in,
                              void* d_out, int out_size, void* d_ws, size_t ws_size,
                              hipStream_t stream) {
  const float* x        = (const float*)d_in[0];
  const float* proj_mat = (const float*)d_in[1];
  const float* mix_mat  = (const float*)d_in[2];
  const float* emb      = (const float*)d_in[3];
  float* out = (float*)d_out;

  char* ws = (char*)d_ws;
  short* projA = (short*)ws;                          // bf16 [4096][256] = 2 MB
  float* pi    = (float*)(ws + (2u << 20));           // [4096]
  float* w     = (float*)(ws + (2u << 20) + 16384);   // [4096]
  short* embB  = (short*)(ws + (4u << 20));           // bf16 [100096][256] = 48.9 MB
  float* part  = (float*)(ws + (4u << 20) + (size_t)VPAD * 512);  // [391][4096] = 6.4 MB

  dim3 g1(16, 16);
  proj_kernel<<<g1, 256, 0, stream>>>(x, proj_mat, projA);
  pi_kernel<<<4, 256, 0, stream>>>(x, mix_mat, pi);
  embB_kernel<<<VPAD * 32 / 256, 256, 0, stream>>>(emb, embB);

  dim3 gg(16, NVB);
  mos_gemm8<0><<<gg, 512, 0, stream>>>(projA, embB, nullptr, part, nullptr);
  reduce_w<<<16, 256, 0, stream>>>(part, pi, w);
  mos_gemm8<1><<<gg, 512, 0, stream>>>(projA, embB, w, nullptr, out);
}